// Round 3
// baseline (738.132 us; speedup 1.0000x reference)
//
#include <hip/hip_runtime.h>

#define N_NODES 100000
#define N_EDGES 3200000
#define N_GRAPHS 512
#define VOCAB 128
#define HID 16
#define LABELS 10

// deg[dst]++ for every edge (self-loops handled analytically as +1 later)
__global__ void k_degree(const int* __restrict__ dst, float* __restrict__ deg) {
    int e = blockIdx.x * blockDim.x + threadIdx.x;
    if (e < N_EDGES) atomicAdd(&deg[dst[e]], 1.0f);
}

// dinv = rsqrt(deg + 1)  (the +1 is the self-loop; deg+1 > 0 always)
__global__ void k_dinv(float* __restrict__ deg) {
    int n = blockIdx.x * blockDim.x + threadIdx.x;
    if (n < N_NODES) deg[n] = rsqrtf(deg[n] + 1.0f);
}

// table = emb @ W1  (128 x 16) — folds the embedding lookup and layer-1 matmul
__global__ void k_table(const float* __restrict__ emb, const float* __restrict__ W1,
                        float* __restrict__ table) {
    int t = blockIdx.x * blockDim.x + threadIdx.x;
    if (t >= VOCAB * HID) return;
    int v = t / HID, k = t % HID;
    float acc = 0.f;
    for (int j = 0; j < HID; ++j) acc += emb[v * HID + j] * W1[j * HID + k];
    table[t] = acc;
}

// hw1[n] = table[x[n]];  out1[n] = hw1[n] * dinv[n]^2  (self-loop term, non-atomic init)
__global__ void k_init(const int* __restrict__ x, const float* __restrict__ table,
                       const float* __restrict__ dinv,
                       float* __restrict__ hw, float* __restrict__ out) {
    int t = blockIdx.x * blockDim.x + threadIdx.x;
    int n = t >> 4, k = t & 15;
    if (n >= N_NODES) return;
    float val = table[x[n] * HID + k];
    float dv = dinv[n];
    hw[t]  = val;            // t == n*HID + k
    out[t] = val * dv * dv;
}

// out[dst] += hw[src] * dinv[src]*dinv[dst]   — 16 threads per edge (lane = feature)
__global__ void k_edge(const int* __restrict__ src, const int* __restrict__ dst,
                       const float* __restrict__ dinv,
                       const float* __restrict__ hw, float* __restrict__ out) {
    int t = blockIdx.x * blockDim.x + threadIdx.x;
    int e = t >> 4, k = t & 15;
    if (e >= N_EDGES) return;
    int s = src[e], d = dst[e];
    float nm = dinv[s] * dinv[d];
    atomicAdd(&out[d * HID + k], hw[s * HID + k] * nm);
}

// h1 = relu(out1 + b1); hw2 = h1 @ W2; out2 = hw2 * dinv^2 (self-loop init).
// hw/out are read-then-overwritten per thread-owned row, so aliasing layer1/layer2
// buffers is safe. W2, b1 staged in LDS (block = 256 = HID*HID threads).
__global__ void k_update(float* __restrict__ hw, float* __restrict__ out,
                         const float* __restrict__ dinv,
                         const float* __restrict__ b1, const float* __restrict__ W2) {
    __shared__ float sW[HID * HID];
    __shared__ float sb[HID];
    int lt = threadIdx.x;
    if (lt < HID * HID) sW[lt] = W2[lt];
    if (lt < HID) sb[lt] = b1[lt];
    __syncthreads();
    int n = blockIdx.x * blockDim.x + lt;
    if (n >= N_NODES) return;
    float h[HID];
#pragma unroll
    for (int j = 0; j < HID; ++j) h[j] = fmaxf(out[n * HID + j] + sb[j], 0.f);
    float dv = dinv[n], dv2 = dv * dv;
#pragma unroll
    for (int k = 0; k < HID; ++k) {
        float acc = 0.f;
#pragma unroll
        for (int j = 0; j < HID; ++j) acc += h[j] * sW[j * HID + k];
        hw[n * HID + k]  = acc;
        out[n * HID + k] = acc * dv2;
    }
}

// h2 = relu(out2 + b2); pooled-sum by graph + node counts
__global__ void k_final(const float* __restrict__ out, const int* __restrict__ batch,
                        const float* __restrict__ b2,
                        float* __restrict__ psum, float* __restrict__ cnt) {
    int t = blockIdx.x * blockDim.x + threadIdx.x;
    int n = t >> 4, k = t & 15;
    if (n >= N_NODES) return;
    float h = fmaxf(out[t] + b2[k], 0.f);
    int g = batch[n];
    atomicAdd(&psum[g * HID + k], h);
    if (k == 0) atomicAdd(&cnt[g], 1.0f);
}

// logits = (psum / max(cnt,1)) @ Wc + bc
__global__ void k_classify(const float* __restrict__ psum, const float* __restrict__ cnt,
                           const float* __restrict__ Wc, const float* __restrict__ bc,
                           float* __restrict__ outp) {
    int t = blockIdx.x * blockDim.x + threadIdx.x;
    if (t >= N_GRAPHS * LABELS) return;
    int g = t / LABELS, l = t % LABELS;
    float c = fmaxf(cnt[g], 1.0f);
    float acc = bc[l];
    for (int k = 0; k < HID; ++k) acc += (psum[g * HID + k] / c) * Wc[k * LABELS + l];
    outp[t] = acc;
}

extern "C" void kernel_launch(void* const* d_in, const int* in_sizes, int n_in,
                              void* d_out, int out_size, void* d_ws, size_t ws_size,
                              hipStream_t stream) {
    const int*   x     = (const int*)d_in[0];
    const int*   ei    = (const int*)d_in[1];
    const int*   batch = (const int*)d_in[2];
    const float* emb   = (const float*)d_in[3];
    const float* W1    = (const float*)d_in[4];
    const float* b1    = (const float*)d_in[5];
    const float* W2    = (const float*)d_in[6];
    const float* b2    = (const float*)d_in[7];
    const float* Wc    = (const float*)d_in[8];
    const float* bc    = (const float*)d_in[9];
    float* outp = (float*)d_out;
    float* ws   = (float*)d_ws;

    // workspace layout (floats): ~13.2 MB total
    float* dinv  = ws;                               // N_NODES (deg, then dinv in-place)
    float* hw    = dinv + N_NODES;                   // N_NODES*HID  (hw1, then hw2)
    float* out   = hw   + (size_t)N_NODES * HID;     // N_NODES*HID  (out1, then out2)
    float* table = out  + (size_t)N_NODES * HID;     // VOCAB*HID
    float* psum  = table + VOCAB * HID;              // N_GRAPHS*HID
    float* cnt   = psum  + N_GRAPHS * HID;           // N_GRAPHS

    const int* srcp = ei;            // edge_index row 0
    const int* dstp = ei + N_EDGES;  // edge_index row 1

    hipMemsetAsync(dinv, 0, N_NODES * sizeof(float), stream);
    hipMemsetAsync(psum, 0, (N_GRAPHS * HID + N_GRAPHS) * sizeof(float), stream);

    k_degree<<<(N_EDGES + 255) / 256, 256, 0, stream>>>(dstp, dinv);
    k_dinv<<<(N_NODES + 255) / 256, 256, 0, stream>>>(dinv);
    k_table<<<(VOCAB * HID + 255) / 256, 256, 0, stream>>>(emb, W1, table);
    k_init<<<(N_NODES * HID + 255) / 256, 256, 0, stream>>>(x, table, dinv, hw, out);
    k_edge<<<(int)(((size_t)N_EDGES * HID + 255) / 256), 256, 0, stream>>>(srcp, dstp, dinv, hw, out);
    k_update<<<(N_NODES + 255) / 256, 256, 0, stream>>>(hw, out, dinv, b1, W2);
    k_edge<<<(int)(((size_t)N_EDGES * HID + 255) / 256), 256, 0, stream>>>(srcp, dstp, dinv, hw, out);
    k_final<<<(N_NODES * HID + 255) / 256, 256, 0, stream>>>(out, batch, b2, psum, cnt);
    k_classify<<<(N_GRAPHS * LABELS + 255) / 256, 256, 0, stream>>>(psum, cnt, Wc, bc, outp);
}